// Round 4
// baseline (1203.262 us; speedup 1.0000x reference)
//
#include <hip/hip_runtime.h>

#define NN 50000
#define EE 600000
#define DD 128
#define HH 256
#define LL 6
#define NB 49   // ceil(NN/1024)

typedef short s16x8 __attribute__((ext_vector_type(8)));
typedef float f32x4 __attribute__((ext_vector_type(4)));

__device__ __forceinline__ float bf2f(unsigned short u){
  unsigned int x = ((unsigned int)u) << 16; float f; __builtin_memcpy(&f, &x, 4); return f;
}
__device__ __forceinline__ unsigned short f2bf(float f){
  unsigned int x; __builtin_memcpy(&x, &f, 4);
  unsigned int lsb = (x >> 16) & 1u; x += 0x7fffu + lsb; return (unsigned short)(x >> 16);
}
__device__ __forceinline__ float wave_sum(float v){
  #pragma unroll
  for (int off = 32; off >= 1; off >>= 1) v += __shfl_xor(v, off, 64);
  return v;
}
__device__ __forceinline__ unsigned short f2h(float f){
  _Float16 h = (_Float16)f; unsigned short u; __builtin_memcpy(&u, &h, 2); return u;
}
__device__ __forceinline__ float h2f(unsigned short u){
  _Float16 h; __builtin_memcpy(&h, &u, 2); return (float)h;
}

// ---------------- dtype detection (device-side, capture-safe) ----------------
__global__ void k_detect(const unsigned short* __restrict__ xh,
                         const unsigned int* __restrict__ ew,
                         int* __restrict__ flags){
  __shared__ int s_bad, s_nz;
  int t = threadIdx.x;
  if (t == 0){ s_bad = 0; s_nz = 0; }
  __syncthreads();
  int bad = 0;
  for (int i = t; i < 512; i += 256){
    unsigned e = (xh[i] >> 7) & 0xffu;
    if (e < 96u || e > 135u) bad = 1;
  }
  if (bad) atomicOr(&s_bad, 1);
  int nz = 0;
  for (int i = t; i < 1024; i += 256)
    if ((i & 1) && ew[i] != 0u) nz = 1;
  if (nz) atomicOr(&s_nz, 1);
  __syncthreads();
  if (t == 0){
    flags[0] = s_bad ? 1 : 0;
    flags[1] = s_nz ? 0 : 1;
  }
}

__global__ void k_cvt_edges(const void* __restrict__ ei, const int* __restrict__ flags,
                            int* __restrict__ s32, int* __restrict__ d32){
  int e = blockIdx.x*256 + threadIdx.x;
  if (e >= EE) return;
  int sv, dv;
  if (flags[1]){
    const long long* p = (const long long*)ei;
    sv = (int)p[e]; dv = (int)p[EE + e];
  } else {
    const int* p = (const int*)ei;
    sv = p[e]; dv = p[EE + e];
  }
  s32[e] = ((unsigned)sv < (unsigned)NN) ? sv : 0;
  d32[e] = ((unsigned)dv < (unsigned)NN) ? dv : 0;
}

// ---------------- CSR build ----------------
__global__ void k_hist(const int* __restrict__ dst, int* __restrict__ deg){
  int e = blockIdx.x*256 + threadIdx.x;
  if (e < EE) atomicAdd(&deg[dst[e]], 1);
}

__global__ void k_blocksum(const int* __restrict__ deg, int* __restrict__ bsum){
  __shared__ int ws[4];
  int t = threadIdx.x, b = blockIdx.x;
  int s = 0;
  int i0 = b*1024 + t*4;
  #pragma unroll
  for (int j=0;j<4;j++){ int i = i0+j; if (i < NN) s += deg[i]; }
  #pragma unroll
  for (int off=32; off>=1; off>>=1) s += __shfl_xor(s, off, 64);
  if ((t&63)==0) ws[t>>6] = s;
  __syncthreads();
  if (t==0) bsum[b] = ws[0]+ws[1]+ws[2]+ws[3];
}

__global__ void k_scanb(const int* __restrict__ bsum, int* __restrict__ boff, int* __restrict__ rowptr){
  int lane = threadIdx.x;
  int v = (lane < NB) ? bsum[lane] : 0;
  int inc = v;
  #pragma unroll
  for (int off=1; off<64; off<<=1){ int u = __shfl_up(inc, off, 64); if (lane>=off) inc += u; }
  if (lane < NB) boff[lane] = inc - v;
  if (lane == 63) rowptr[NN] = inc;
}

__global__ void k_scanscatter(const int* __restrict__ deg, const int* __restrict__ boff,
                              int* __restrict__ rowptr, int* __restrict__ pos){
  __shared__ int ws[4];
  int t = threadIdx.x, b = blockIdx.x;
  int lane = t & 63, wid = t >> 6;
  int i0 = b*1024 + t*4;
  int d[4];
  #pragma unroll
  for (int j=0;j<4;j++){ int i=i0+j; d[j] = (i<NN)? deg[i] : 0; }
  int tot = d[0]+d[1]+d[2]+d[3];
  int inc = tot;
  #pragma unroll
  for (int off=1; off<64; off<<=1){ int u = __shfl_up(inc, off, 64); if (lane>=off) inc += u; }
  if (lane==63) ws[wid] = inc;
  __syncthreads();
  int woff = 0;
  for (int w=0; w<wid; w++) woff += ws[w];
  int base = boff[b] + woff + (inc - tot);
  int pre = 0;
  #pragma unroll
  for (int j=0;j<4;j++){
    int i = i0+j;
    if (i<NN){ rowptr[i] = base + pre; pos[i] = base + pre; }
    pre += d[j];
  }
}

__global__ void k_fill(const int* __restrict__ src, const int* __restrict__ dst,
                       int* __restrict__ pos, int* __restrict__ csr){
  int e = blockIdx.x*256 + threadIdx.x;
  if (e < EE){
    int d = dst[e];
    int p = atomicAdd(&pos[d], 1);
    csr[p] = src[e];
  }
}

// ---------------- weight prep: transpose + hi/lo bf16 split ----------------
__global__ void k_prep_w(const int* __restrict__ flags,
    const void* __restrict__ encW, const void* __restrict__ linW1,
    const void* __restrict__ W1, const void* __restrict__ W2,
    unsigned short* __restrict__ ph, unsigned short* __restrict__ pl)
{
  int idx = blockIdx.x*256 + threadIdx.x;   // grid covers 425984
  int fp32 = flags[0];
  const void* src; int off;
  if (idx < 16384){ int n=idx>>7, k=idx&127; src=encW; off=k*128+n; }
  else if (idx < 32768){ int o=idx-16384; int n=o>>7, k=o&127; src=linW1; off=k*128+n; }
  else if (idx < 229376){ int o=idx-32768; int l=o>>15, r=o&32767; int n=r>>7, k=r&127; src=W1; off=l*32768+k*256+n; }
  else { int o=idx-229376; int l=o>>15, r=o&32767; int n=r>>8, k=r&255; src=W2; off=l*32768+k*128+n; }
  float w = fp32 ? ((const float*)src)[off] : bf2f(((const unsigned short*)src)[off]);
  unsigned short h = f2bf(w);
  ph[idx] = h;
  pl[idx] = f2bf(w - bf2f(h));
}

// small params -> fp32, concatenated
#define SM_ENCB 0
#define SM_LNG 128
#define SM_LNB 896
#define SM_TV 1664
#define SM_B1 1670
#define SM_MG 3206
#define SM_MB 4742
#define SM_B2 6278
#define SM_LINB1 7046
#define SM_LINW2 7174
#define SM_LINB2 7430
#define SM_TOT 7432
__global__ void k_prep_small(const int* __restrict__ flags,
    const void* s0, const void* s1, const void* s2, const void* s3,
    const void* s4, const void* s5, const void* s6, const void* s7,
    const void* s8, const void* s9, const void* s10, float* __restrict__ out)
{
  int i = blockIdx.x*256 + threadIdx.x;
  if (i >= SM_TOT) return;
  int fp32 = flags[0];
  const void* src; int off;
  if      (i < SM_LNG)  { src=s0;  off=i; }
  else if (i < SM_LNB)  { src=s1;  off=i-SM_LNG; }
  else if (i < SM_TV)   { src=s2;  off=i-SM_LNB; }
  else if (i < SM_B1)   { src=s3;  off=i-SM_TV; }
  else if (i < SM_MG)   { src=s4;  off=i-SM_B1; }
  else if (i < SM_MB)   { src=s5;  off=i-SM_MG; }
  else if (i < SM_B2)   { src=s6;  off=i-SM_MB; }
  else if (i < SM_LINB1){ src=s7;  off=i-SM_B2; }
  else if (i < SM_LINW2){ src=s8;  off=i-SM_LINB1; }
  else if (i < SM_LINB2){ src=s9;  off=i-SM_LINW2; }
  else                  { src=s10; off=i-SM_LINB2; }
  out[i] = fp32 ? ((const float*)src)[off] : bf2f(((const unsigned short*)src)[off]);
}

// ---------------- generic MFMA GEMM (enc + head lin1) ------------------------
template<int K, int EPI>
__global__ __launch_bounds__(256, 4) void k_gemm(const void* __restrict__ Ap,
    const unsigned short* __restrict__ WTh, const unsigned short* __restrict__ WTl,
    const float* __restrict__ bias, float* __restrict__ C,
    int ldc, int colOff, int M, const int* __restrict__ flags, int aExtern)
{
  __shared__ __align__(16) short lAh[64*72];
  __shared__ __align__(16) short lAl[64*72];
  __shared__ __align__(16) short lW[128*72];

  const int tid = threadIdx.x;
  const int lane = tid & 63, wid = tid >> 6;
  const int rowb = blockIdx.x * 64;
  const int fp32m = flags[0];
  const int a_bf = aExtern && !fp32m;

  f32x4 acc[4][2];
  #pragma unroll
  for (int a=0;a<4;a++)
    #pragma unroll
    for (int c=0;c<2;c++){ acc[a][c][0]=0.f; acc[a][c][1]=0.f; acc[a][c][2]=0.f; acc[a][c][3]=0.f; }

  const int nPass = fp32m ? 2 : 1;
  for (int pass = 0; pass < nPass; ++pass){
    const unsigned short* Wp = pass ? WTl : WTh;
    const bool useAl = (pass == 0) && !a_bf;
    for (int kc = 0; kc < K/64; ++kc){
      {
        const int cv = tid & 15, r0 = tid >> 4;
        #pragma unroll
        for (int p = 0; p < 4; ++p){
          int row = p*16 + r0;
          int grow = rowb + row;
          if (a_bf){
            uint2 d; d.x = 0u; d.y = 0u;
            if (grow < M) d = *(const uint2*)((const unsigned short*)Ap + (size_t)grow*K + kc*64 + cv*4);
            *(uint2*)&lAh[row*72 + cv*4] = d;
          } else {
            float4 v = make_float4(0.f,0.f,0.f,0.f);
            if (grow < M) v = *(const float4*)((const float*)Ap + (size_t)grow*K + kc*64 + cv*4);
            float vv[4] = {v.x, v.y, v.z, v.w};
            unsigned short hb[4], lb[4];
            #pragma unroll
            for (int c=0;c<4;c++){ hb[c] = f2bf(vv[c]); lb[c] = f2bf(vv[c] - bf2f(hb[c])); }
            uint2 hp, lp;
            hp.x = (unsigned)hb[0] | ((unsigned)hb[1]<<16); hp.y = (unsigned)hb[2] | ((unsigned)hb[3]<<16);
            lp.x = (unsigned)lb[0] | ((unsigned)lb[1]<<16); lp.y = (unsigned)lb[2] | ((unsigned)lb[3]<<16);
            *(uint2*)&lAh[row*72 + cv*4] = hp;
            if (useAl) *(uint2*)&lAl[row*72 + cv*4] = lp;
          }
        }
        const int kv = tid & 15, n0 = tid >> 4;
        #pragma unroll
        for (int p = 0; p < 8; ++p){
          int n = p*16 + n0;
          *(uint2*)&lW[n*72 + kv*4] = *(const uint2*)(Wp + (size_t)n*K + kc*64 + kv*4);
        }
      }
      __syncthreads();
      const int mi = lane & 15, q = lane >> 4;
      #pragma unroll
      for (int ks = 0; ks < 2; ++ks){
        const int koff = ks*32 + q*8;
        s16x8 ah[4], al[4], bw[2];
        #pragma unroll
        for (int rt=0; rt<4; rt++){
          ah[rt] = *(const s16x8*)&lAh[(rt*16+mi)*72 + koff];
          if (useAl) al[rt] = *(const s16x8*)&lAl[(rt*16+mi)*72 + koff];
        }
        #pragma unroll
        for (int ct=0; ct<2; ct++)
          bw[ct] = *(const s16x8*)&lW[(wid*32 + ct*16 + mi)*72 + koff];
        #pragma unroll
        for (int rt=0; rt<4; rt++)
          #pragma unroll
          for (int ct=0; ct<2; ct++){
            acc[rt][ct] = __builtin_amdgcn_mfma_f32_16x16x32_bf16(ah[rt], bw[ct], acc[rt][ct], 0,0,0);
            if (useAl)
              acc[rt][ct] = __builtin_amdgcn_mfma_f32_16x16x32_bf16(al[rt], bw[ct], acc[rt][ct], 0,0,0);
          }
      }
      __syncthreads();
    }
  }
  const int mi = lane & 15, q = lane >> 4;
  #pragma unroll
  for (int ct=0; ct<2; ct++){
    const int col = colOff + wid*32 + ct*16 + mi;
    const float bf = bias[col];
    #pragma unroll
    for (int rt=0; rt<4; rt++){
      #pragma unroll
      for (int r=0; r<4; r++){
        int row = rowb + rt*16 + q*4 + r;
        if (row < M){
          float v = acc[rt][ct][r] + bf;
          size_t o = (size_t)row*ldc + col;
          if (EPI == 1) v = fmaxf(v, 0.f);
          if (EPI == 2) C[o] += v; else C[o] = v;
        }
      }
    }
  }
}

// ---------------- fused W1 GEMM + LN + relu: z = relu(LN(A@W1 + b1)) --------
// tile 64 rows x 256 cols, K=128, BK=32. A fp32 internal (split in staging).
__global__ __launch_bounds__(256, 2) void k_gemm1(const float* __restrict__ Ap,
    const unsigned short* __restrict__ WTh, const unsigned short* __restrict__ WTl,
    const float* __restrict__ bias, const float* __restrict__ gam, const float* __restrict__ bet,
    float* __restrict__ z, int M, const int* __restrict__ flags)
{
  __shared__ __align__(16) short lAh[64*40];
  __shared__ __align__(16) short lAl[64*40];
  __shared__ __align__(16) short lW[256*40];
  __shared__ float2 sred[4][64];

  const int tid = threadIdx.x, lane = tid & 63, wid = tid >> 6;
  const int mi = lane & 15, q = lane >> 4;
  const int rowb = blockIdx.x * 64;

  f32x4 acc[4][4];
  #pragma unroll
  for (int a=0;a<4;a++)
    #pragma unroll
    for (int c=0;c<4;c++){ acc[a][c][0]=0.f; acc[a][c][1]=0.f; acc[a][c][2]=0.f; acc[a][c][3]=0.f; }

  const int nPass = flags[0] ? 2 : 1;
  for (int pass = 0; pass < nPass; ++pass){
    const unsigned short* Wp = pass ? WTl : WTh;
    const bool useAl = (pass == 0);
    for (int kc = 0; kc < 4; ++kc){
      {
        const int cv = tid & 7, r0 = tid >> 3;   // 32 rows per pass
        #pragma unroll
        for (int p = 0; p < 2; ++p){
          int row = p*32 + r0, grow = rowb + row;
          float4 v = make_float4(0.f,0.f,0.f,0.f);
          if (grow < M) v = *(const float4*)(Ap + (size_t)grow*128 + kc*32 + cv*4);
          float vv[4] = {v.x, v.y, v.z, v.w};
          unsigned short hb[4], lb[4];
          #pragma unroll
          for (int c=0;c<4;c++){ hb[c] = f2bf(vv[c]); lb[c] = f2bf(vv[c] - bf2f(hb[c])); }
          uint2 hp, lp;
          hp.x = (unsigned)hb[0] | ((unsigned)hb[1]<<16); hp.y = (unsigned)hb[2] | ((unsigned)hb[3]<<16);
          lp.x = (unsigned)lb[0] | ((unsigned)lb[1]<<16); lp.y = (unsigned)lb[2] | ((unsigned)lb[3]<<16);
          *(uint2*)&lAh[row*40 + cv*4] = hp;
          if (useAl) *(uint2*)&lAl[row*40 + cv*4] = lp;
        }
        const int kv = tid & 7, n0 = tid >> 3;
        #pragma unroll
        for (int p = 0; p < 8; ++p){
          int n = p*32 + n0;
          *(uint2*)&lW[n*40 + kv*4] = *(const uint2*)(Wp + (size_t)n*128 + kc*32 + kv*4);
        }
      }
      __syncthreads();
      const int koff = q*8;
      s16x8 ah[4], al[4], bw[4];
      #pragma unroll
      for (int rt=0; rt<4; rt++){
        ah[rt] = *(const s16x8*)&lAh[(rt*16+mi)*40 + koff];
        if (useAl) al[rt] = *(const s16x8*)&lAl[(rt*16+mi)*40 + koff];
      }
      #pragma unroll
      for (int ct=0; ct<4; ct++)
        bw[ct] = *(const s16x8*)&lW[(wid*64 + ct*16 + mi)*40 + koff];
      #pragma unroll
      for (int rt=0; rt<4; rt++)
        #pragma unroll
        for (int ct=0; ct<4; ct++){
          acc[rt][ct] = __builtin_amdgcn_mfma_f32_16x16x32_bf16(ah[rt], bw[ct], acc[rt][ct], 0,0,0);
          if (useAl)
            acc[rt][ct] = __builtin_amdgcn_mfma_f32_16x16x32_bf16(al[rt], bw[ct], acc[rt][ct], 0,0,0);
        }
      __syncthreads();
    }
  }
  // + bias
  #pragma unroll
  for (int ct=0; ct<4; ct++){
    const float bf = bias[wid*64 + ct*16 + mi];
    #pragma unroll
    for (int rt=0; rt<4; rt++)
      #pragma unroll
      for (int r=0; r<4; r++) acc[rt][ct][r] += bf;
  }
  // row stats (sum, sumsq) over this wave's 64 cols -> LDS
  #pragma unroll
  for (int rt=0; rt<4; rt++)
    #pragma unroll
    for (int r=0; r<4; r++){
      float s = 0.f, s2 = 0.f;
      #pragma unroll
      for (int ct=0; ct<4; ct++){ float v = acc[rt][ct][r]; s += v; s2 += v*v; }
      #pragma unroll
      for (int off=1; off<16; off<<=1){ s += __shfl_xor(s, off, 64); s2 += __shfl_xor(s2, off, 64); }
      if (mi == 0) sred[wid][rt*16 + q*4 + r] = make_float2(s, s2);
    }
  __syncthreads();
  float mean[4][4], rsv[4][4];
  #pragma unroll
  for (int rt=0; rt<4; rt++)
    #pragma unroll
    for (int r=0; r<4; r++){
      int rl = rt*16 + q*4 + r;
      float2 t0 = sred[0][rl], t1 = sred[1][rl], t2 = sred[2][rl], t3 = sred[3][rl];
      float s = t0.x + t1.x + t2.x + t3.x;
      float s2 = t0.y + t1.y + t2.y + t3.y;
      float m = s * (1.f/256.f);
      float var = s2 * (1.f/256.f) - m*m;
      mean[rt][r] = m;
      rsv[rt][r] = rsqrtf(var + 1e-5f);
    }
  #pragma unroll
  for (int ct=0; ct<4; ct++){
    const int col = wid*64 + ct*16 + mi;
    const float gc = gam[col], bc = bet[col];
    #pragma unroll
    for (int rt=0; rt<4; rt++)
      #pragma unroll
      for (int r=0; r<4; r++){
        int row = rowb + rt*16 + q*4 + r;
        if (row < M){
          float v = (acc[rt][ct][r] - mean[rt][r]) * rsv[rt][r] * gc + bc;
          z[(size_t)row*256 + col] = fmaxf(v, 0.f);
        }
      }
  }
}

// ---------------- fused W2 GEMM + residual + next-layer preLN + msg ----------
// tile 64 rows x 128 cols, K=256, BK=32. h += A@W2 + b2; if doLN: msg = fp16(relu(LN(h))+1e-7)
__global__ __launch_bounds__(256, 2) void k_gemm2(const float* __restrict__ Ap,
    const unsigned short* __restrict__ WTh, const unsigned short* __restrict__ WTl,
    const float* __restrict__ bias, float* __restrict__ h,
    const float* __restrict__ gam, const float* __restrict__ bet,
    unsigned short* __restrict__ msg, int M, const int* __restrict__ flags, int doLN)
{
  __shared__ __align__(16) short lAh[64*40];
  __shared__ __align__(16) short lAl[64*40];
  __shared__ __align__(16) short lW[128*40];
  __shared__ float2 sred[4][64];

  const int tid = threadIdx.x, lane = tid & 63, wid = tid >> 6;
  const int mi = lane & 15, q = lane >> 4;
  const int rowb = blockIdx.x * 64;

  f32x4 acc[4][2];
  #pragma unroll
  for (int a=0;a<4;a++)
    #pragma unroll
    for (int c=0;c<2;c++){ acc[a][c][0]=0.f; acc[a][c][1]=0.f; acc[a][c][2]=0.f; acc[a][c][3]=0.f; }

  const int nPass = flags[0] ? 2 : 1;
  for (int pass = 0; pass < nPass; ++pass){
    const unsigned short* Wp = pass ? WTl : WTh;
    const bool useAl = (pass == 0);
    for (int kc = 0; kc < 8; ++kc){
      {
        const int cv = tid & 7, r0 = tid >> 3;
        #pragma unroll
        for (int p = 0; p < 2; ++p){
          int row = p*32 + r0, grow = rowb + row;
          float4 v = make_float4(0.f,0.f,0.f,0.f);
          if (grow < M) v = *(const float4*)(Ap + (size_t)grow*256 + kc*32 + cv*4);
          float vv[4] = {v.x, v.y, v.z, v.w};
          unsigned short hb[4], lb[4];
          #pragma unroll
          for (int c=0;c<4;c++){ hb[c] = f2bf(vv[c]); lb[c] = f2bf(vv[c] - bf2f(hb[c])); }
          uint2 hp, lp;
          hp.x = (unsigned)hb[0] | ((unsigned)hb[1]<<16); hp.y = (unsigned)hb[2] | ((unsigned)hb[3]<<16);
          lp.x = (unsigned)lb[0] | ((unsigned)lb[1]<<16); lp.y = (unsigned)lb[2] | ((unsigned)lb[3]<<16);
          *(uint2*)&lAh[row*40 + cv*4] = hp;
          if (useAl) *(uint2*)&lAl[row*40 + cv*4] = lp;
        }
        const int kv = tid & 7, n0 = tid >> 3;
        #pragma unroll
        for (int p = 0; p < 4; ++p){
          int n = p*32 + n0;
          *(uint2*)&lW[n*40 + kv*4] = *(const uint2*)(Wp + (size_t)n*256 + kc*32 + kv*4);
        }
      }
      __syncthreads();
      const int koff = q*8;
      s16x8 ah[4], al[4], bw[2];
      #pragma unroll
      for (int rt=0; rt<4; rt++){
        ah[rt] = *(const s16x8*)&lAh[(rt*16+mi)*40 + koff];
        if (useAl) al[rt] = *(const s16x8*)&lAl[(rt*16+mi)*40 + koff];
      }
      #pragma unroll
      for (int ct=0; ct<2; ct++)
        bw[ct] = *(const s16x8*)&lW[(wid*32 + ct*16 + mi)*40 + koff];
      #pragma unroll
      for (int rt=0; rt<4; rt++)
        #pragma unroll
        for (int ct=0; ct<2; ct++){
          acc[rt][ct] = __builtin_amdgcn_mfma_f32_16x16x32_bf16(ah[rt], bw[ct], acc[rt][ct], 0,0,0);
          if (useAl)
            acc[rt][ct] = __builtin_amdgcn_mfma_f32_16x16x32_bf16(al[rt], bw[ct], acc[rt][ct], 0,0,0);
        }
      __syncthreads();
    }
  }
  // residual add + write h; keep hnew in acc
  #pragma unroll
  for (int ct=0; ct<2; ct++){
    const int col = wid*32 + ct*16 + mi;
    const float bf = bias[col];
    #pragma unroll
    for (int rt=0; rt<4; rt++)
      #pragma unroll
      for (int r=0; r<4; r++){
        int row = rowb + rt*16 + q*4 + r;
        if (row < M){
          float hv = acc[rt][ct][r] + bf + h[(size_t)row*128 + col];
          h[(size_t)row*128 + col] = hv;
          acc[rt][ct][r] = hv;
        }
      }
  }
  if (!doLN) return;
  #pragma unroll
  for (int rt=0; rt<4; rt++)
    #pragma unroll
    for (int r=0; r<4; r++){
      float s = 0.f, s2 = 0.f;
      #pragma unroll
      for (int ct=0; ct<2; ct++){ float v = acc[rt][ct][r]; s += v; s2 += v*v; }
      #pragma unroll
      for (int off=1; off<16; off<<=1){ s += __shfl_xor(s, off, 64); s2 += __shfl_xor(s2, off, 64); }
      if (mi == 0) sred[wid][rt*16 + q*4 + r] = make_float2(s, s2);
    }
  __syncthreads();
  float mean[4][4], rsv[4][4];
  #pragma unroll
  for (int rt=0; rt<4; rt++)
    #pragma unroll
    for (int r=0; r<4; r++){
      int rl = rt*16 + q*4 + r;
      float2 t0 = sred[0][rl], t1 = sred[1][rl], t2 = sred[2][rl], t3 = sred[3][rl];
      float s = t0.x + t1.x + t2.x + t3.x;
      float s2 = t0.y + t1.y + t2.y + t3.y;
      float m = s * (1.f/128.f);
      float var = s2 * (1.f/128.f) - m*m;
      mean[rt][r] = m;
      rsv[rt][r] = rsqrtf(var + 1e-5f);
    }
  #pragma unroll
  for (int ct=0; ct<2; ct++){
    const int col = wid*32 + ct*16 + mi;
    const float gc = gam[col], bc = bet[col];
    #pragma unroll
    for (int rt=0; rt<4; rt++)
      #pragma unroll
      for (int r=0; r<4; r++){
        int row = rowb + rt*16 + q*4 + r;
        if (row < M){
          float g = fmaxf((acc[rt][ct][r] - mean[rt][r]) * rsv[rt][r] * gc + bc, 0.f);
          msg[(size_t)row*128 + col] = f2h(g + 1e-7f);
        }
      }
  }
}

// ---------------- layer-0 pre-LN: msg = fp16(relu(LN(h)) + 1e-7) -------------
__global__ __launch_bounds__(256,4) void k_preln0(const float* __restrict__ h,
    const float* __restrict__ gam, const float* __restrict__ bet,
    unsigned short* __restrict__ msg)
{
  int wid = threadIdx.x >> 6, lane = threadIdx.x & 63;
  int row = blockIdx.x*4 + wid;
  float2 v = ((const float2*)(h + (size_t)row*DD))[lane];
  float mean = wave_sum(v.x+v.y) * (1.f/128.f);
  float d0 = v.x-mean, d1 = v.y-mean;
  float var = wave_sum(d0*d0 + d1*d1) * (1.f/128.f);
  float rs = rsqrtf(var + 1e-5f);
  float o0 = fmaxf(d0*rs*gam[2*lane]   + bet[2*lane],   0.f);
  float o1 = fmaxf(d1*rs*gam[2*lane+1] + bet[2*lane+1], 0.f);
  unsigned u = (unsigned)f2h(o0 + 1e-7f) | ((unsigned)f2h(o1 + 1e-7f) << 16);
  ((unsigned*)(msg + (size_t)row*DD))[lane] = u;
}

// ---------------- softmax aggregation: 4 edges/iter, uint4 gather ------------
__global__ __launch_bounds__(256,4) void k_agg(
    const unsigned short* __restrict__ msg,
    const int* __restrict__ rowptr, const int* __restrict__ csr,
    const float* __restrict__ tp, float* __restrict__ outb)
{
  int wid = threadIdx.x>>6, lane = threadIdx.x&63;
  int node = blockIdx.x*4 + wid;
  float t = tp[0];
  int st = rowptr[node], en = rowptr[node+1];
  int quad = lane >> 4, fi = lane & 15;   // lane handles features fi*8..fi*8+7 of edge j+quad
  float l[8], ac[8];
  #pragma unroll
  for (int f=0; f<8; f++){ l[f]=0.f; ac[f]=0.f; }
  for (int base = st; base < en; base += 64){
    int cnt = min(64, en - base);
    int sv = (lane < cnt) ? csr[base + lane] : 0;
    for (int j = 0; j < cnt; j += 4){
      int idx = j + quad;
      int s = __shfl(sv, idx, 64);
      bool val = idx < cnt;
      uint4 u = *(const uint4*)(msg + (size_t)s*DD + fi*8);
      float m[8];
      m[0]=h2f((unsigned short)(u.x&0xffffu)); m[1]=h2f((unsigned short)(u.x>>16));
      m[2]=h2f((unsigned short)(u.y&0xffffu)); m[3]=h2f((unsigned short)(u.y>>16));
      m[4]=h2f((unsigned short)(u.z&0xffffu)); m[5]=h2f((unsigned short)(u.z>>16));
      m[6]=h2f((unsigned short)(u.w&0xffffu)); m[7]=h2f((unsigned short)(u.w>>16));
      #pragma unroll
      for (int f=0; f<8; f++){
        float e = __expf(fminf(m[f]*t, 80.f));
        e = val ? e : 0.f;
        l[f] += e; ac[f] += m[f]*e;
      }
    }
  }
  #pragma unroll
  for (int off=16; off<=32; off<<=1)
    #pragma unroll
    for (int f=0; f<8; f++){ l[f] += __shfl_xor(l[f], off, 64); ac[f] += __shfl_xor(ac[f], off, 64); }
  if (quad == 0){
    uint4 u = *(const uint4*)(msg + (size_t)node*DD + fi*8);
    float m[8];
    m[0]=h2f((unsigned short)(u.x&0xffffu)); m[1]=h2f((unsigned short)(u.x>>16));
    m[2]=h2f((unsigned short)(u.y&0xffffu)); m[3]=h2f((unsigned short)(u.y>>16));
    m[4]=h2f((unsigned short)(u.z&0xffffu)); m[5]=h2f((unsigned short)(u.z>>16));
    m[6]=h2f((unsigned short)(u.w&0xffffu)); m[7]=h2f((unsigned short)(u.w>>16));
    bool has = en > st;
    float o[8];
    #pragma unroll
    for (int f=0; f<8; f++){
      float a = has ? (ac[f] / (l[f] + 1e-16f)) : 0.f;
      o[f] = (m[f] - 1e-7f) + a;
    }
    float4 o0 = make_float4(o[0],o[1],o[2],o[3]);
    float4 o1 = make_float4(o[4],o[5],o[6],o[7]);
    *(float4*)(outb + (size_t)node*DD + fi*8)     = o0;
    *(float4*)(outb + (size_t)node*DD + fi*8 + 4) = o1;
  }
}

// ---------------- head ----------------
__global__ __launch_bounds__(256,4) void k_head2(const float* __restrict__ u,
    const float* __restrict__ w, const float* __restrict__ b,
    void* __restrict__ out, const int* __restrict__ flags)
{
  int wid = threadIdx.x>>6, lane = threadIdx.x&63;
  int row = blockIdx.x*4 + wid;
  const float* ur = u + (size_t)row*DD;
  float u0 = ur[lane], u1 = ur[lane+64];
  float s0 = u0*w[lane*2+0] + u1*w[(lane+64)*2+0];
  float s1 = u0*w[lane*2+1] + u1*w[(lane+64)*2+1];
  s0 = wave_sum(s0); s1 = wave_sum(s1);
  if (lane == 0){
    float o0 = s0 + b[0], o1 = s1 + b[1];
    if (flags[0]){
      ((float*)out)[row*2+0] = o0;
      ((float*)out)[row*2+1] = o1;
    } else {
      ((unsigned short*)out)[row*2+0] = f2bf(o0);
      ((unsigned short*)out)[row*2+1] = f2bf(o1);
    }
  }
}

extern "C" void kernel_launch(void* const* d_in, const int* in_sizes, int n_in,
                              void* d_out, int out_size, void* d_ws, size_t ws_size,
                              hipStream_t stream)
{
  (void)in_sizes; (void)n_in; (void)out_size; (void)ws_size;
  char* ws = (char*)d_ws;
  size_t off = 0;
  auto alloc = [&](size_t bytes) -> char* {
    char* p = ws + off;
    off = (off + bytes + 255) & ~(size_t)255;
    return p;
  };
  int* flags  = (int*)alloc(256);
  float* sm   = (float*)alloc(SM_TOT*4);
  unsigned short* planeH = (unsigned short*)alloc(425984*2);
  unsigned short* planeL = (unsigned short*)alloc(425984*2);
  int* src32  = (int*)alloc((size_t)EE*4);
  int* dst32  = (int*)alloc((size_t)EE*4);
  int* deg    = (int*)alloc((size_t)NN*4);
  int* pos    = (int*)alloc((size_t)NN*4);
  int* rowptr = (int*)alloc((size_t)(NN+1)*4);
  int* csr    = (int*)alloc((size_t)EE*4);
  int* bsum   = (int*)alloc(64*4);
  int* boff   = (int*)alloc(64*4);
  float* h    = (float*)alloc((size_t)NN*128*4);
  float* z    = (float*)alloc((size_t)NN*256*4);
  unsigned short* msgb = (unsigned short*)alloc((size_t)NN*128*2);
  float* ob   = (float*)alloc((size_t)NN*128*4);

  k_detect<<<1,256,0,stream>>>((const unsigned short*)d_in[0], (const unsigned int*)d_in[1], flags);
  k_cvt_edges<<<(EE+255)/256,256,0,stream>>>(d_in[1], flags, src32, dst32);
  hipMemsetAsync(deg, 0, (size_t)NN*4, stream);
  k_hist<<<(EE+255)/256,256,0,stream>>>(dst32, deg);
  k_blocksum<<<NB,256,0,stream>>>(deg, bsum);
  k_scanb<<<1,64,0,stream>>>(bsum, boff, rowptr);
  k_scanscatter<<<NB,256,0,stream>>>(deg, boff, rowptr, pos);
  k_fill<<<(EE+255)/256,256,0,stream>>>(src32, dst32, pos, csr);
  k_prep_w<<<1664,256,0,stream>>>(flags, d_in[2], d_in[13], d_in[7], d_in[11], planeH, planeL);
  k_prep_small<<<30,256,0,stream>>>(flags, d_in[3], d_in[4], d_in[5], d_in[6], d_in[8],
                                    d_in[9], d_in[10], d_in[12], d_in[14], d_in[15], d_in[16], sm);

  const int GB = (NN + 63)/64;  // 782
  // encoder: h = x @ enc_W + enc_b
  k_gemm<128,0><<<GB,256,0,stream>>>((const void*)d_in[0], planeH + 0, planeL + 0,
                                     sm + SM_ENCB, h, 128, 0, NN, flags, 1);
  k_preln0<<<NN/4,256,0,stream>>>(h, sm + SM_LNG, sm + SM_LNB, msgb);
  for (int i = 0; i < LL; ++i){
    k_agg<<<NN/4,256,0,stream>>>(msgb, rowptr, csr, sm + SM_TV + i, ob);
    k_gemm1<<<GB,256,0,stream>>>(ob, planeH + 32768 + i*32768, planeL + 32768 + i*32768,
                                 sm + SM_B1 + i*256, sm + SM_MG + i*256, sm + SM_MB + i*256,
                                 z, NN, flags);
    int nl = (i+1 < LL) ? (i+1) : 0;  // LN params for next layer (unused when doLN=0)
    k_gemm2<<<GB,256,0,stream>>>(z, planeH + 229376 + i*32768, planeL + 229376 + i*32768,
                                 sm + SM_B2 + i*128, h,
                                 sm + SM_LNG + nl*128, sm + SM_LNB + nl*128,
                                 msgb, NN, flags, (i+1 < LL) ? 1 : 0);
  }
  k_gemm<128,1><<<GB,256,0,stream>>>((const void*)h, planeH + 16384, planeL + 16384,
                                     sm + SM_LINB1, ob, 128, 0, NN, flags, 0);
  k_head2<<<NN/4,256,0,stream>>>(ob, sm + SM_LINW2, sm + SM_LINB2, d_out, flags);
}

// Round 5
// 893.624 us; speedup vs baseline: 1.3465x; 1.3465x over previous
//
#include <hip/hip_runtime.h>

#define NN 50000
#define EE 600000
#define DD 128
#define HH 256
#define LL 6
#define NB 49   // ceil(NN/1024)

typedef _Float16 f16x8 __attribute__((ext_vector_type(8)));
typedef float f32x4 __attribute__((ext_vector_type(4)));

__device__ __forceinline__ float bf2f(unsigned short u){
  unsigned int x = ((unsigned int)u) << 16; float f; __builtin_memcpy(&f, &x, 4); return f;
}
__device__ __forceinline__ unsigned short f2bf(float f){
  unsigned int x; __builtin_memcpy(&x, &f, 4);
  unsigned int lsb = (x >> 16) & 1u; x += 0x7fffu + lsb; return (unsigned short)(x >> 16);
}
__device__ __forceinline__ float wave_sum(float v){
  #pragma unroll
  for (int off = 32; off >= 1; off >>= 1) v += __shfl_xor(v, off, 64);
  return v;
}
__device__ __forceinline__ unsigned short f2h(float f){
  _Float16 h = (_Float16)f; unsigned short u; __builtin_memcpy(&u, &h, 2); return u;
}
__device__ __forceinline__ float h2f(unsigned short u){
  _Float16 h; __builtin_memcpy(&h, &u, 2); return (float)h;
}

// ---------------- dtype detection (device-side, capture-safe) ----------------
__global__ void k_detect(const unsigned short* __restrict__ xh,
                         const unsigned int* __restrict__ ew,
                         int* __restrict__ flags){
  __shared__ int s_bad, s_nz;
  int t = threadIdx.x;
  if (t == 0){ s_bad = 0; s_nz = 0; }
  __syncthreads();
  int bad = 0;
  for (int i = t; i < 512; i += 256){
    unsigned e = (xh[i] >> 7) & 0xffu;
    if (e < 96u || e > 135u) bad = 1;
  }
  if (bad) atomicOr(&s_bad, 1);
  int nz = 0;
  for (int i = t; i < 1024; i += 256)
    if ((i & 1) && ew[i] != 0u) nz = 1;
  if (nz) atomicOr(&s_nz, 1);
  __syncthreads();
  if (t == 0){
    flags[0] = s_bad ? 1 : 0;
    flags[1] = s_nz ? 0 : 1;
  }
}

__global__ void k_cvt_edges(const void* __restrict__ ei, const int* __restrict__ flags,
                            int* __restrict__ s32, int* __restrict__ d32){
  int e = blockIdx.x*256 + threadIdx.x;
  if (e >= EE) return;
  int sv, dv;
  if (flags[1]){
    const long long* p = (const long long*)ei;
    sv = (int)p[e]; dv = (int)p[EE + e];
  } else {
    const int* p = (const int*)ei;
    sv = p[e]; dv = p[EE + e];
  }
  s32[e] = ((unsigned)sv < (unsigned)NN) ? sv : 0;
  d32[e] = ((unsigned)dv < (unsigned)NN) ? dv : 0;
}

// ---------------- CSR build ----------------
__global__ void k_hist(const int* __restrict__ dst, int* __restrict__ deg){
  int e = blockIdx.x*256 + threadIdx.x;
  if (e < EE) atomicAdd(&deg[dst[e]], 1);
}

__global__ void k_blocksum(const int* __restrict__ deg, int* __restrict__ bsum){
  __shared__ int ws[4];
  int t = threadIdx.x, b = blockIdx.x;
  int s = 0;
  int i0 = b*1024 + t*4;
  #pragma unroll
  for (int j=0;j<4;j++){ int i = i0+j; if (i < NN) s += deg[i]; }
  #pragma unroll
  for (int off=32; off>=1; off>>=1) s += __shfl_xor(s, off, 64);
  if ((t&63)==0) ws[t>>6] = s;
  __syncthreads();
  if (t==0) bsum[b] = ws[0]+ws[1]+ws[2]+ws[3];
}

__global__ void k_scanb(const int* __restrict__ bsum, int* __restrict__ boff, int* __restrict__ rowptr){
  int lane = threadIdx.x;
  int v = (lane < NB) ? bsum[lane] : 0;
  int inc = v;
  #pragma unroll
  for (int off=1; off<64; off<<=1){ int u = __shfl_up(inc, off, 64); if (lane>=off) inc += u; }
  if (lane < NB) boff[lane] = inc - v;
  if (lane == 63) rowptr[NN] = inc;
}

__global__ void k_scanscatter(const int* __restrict__ deg, const int* __restrict__ boff,
                              int* __restrict__ rowptr, int* __restrict__ pos){
  __shared__ int ws[4];
  int t = threadIdx.x, b = blockIdx.x;
  int lane = t & 63, wid = t >> 6;
  int i0 = b*1024 + t*4;
  int d[4];
  #pragma unroll
  for (int j=0;j<4;j++){ int i=i0+j; d[j] = (i<NN)? deg[i] : 0; }
  int tot = d[0]+d[1]+d[2]+d[3];
  int inc = tot;
  #pragma unroll
  for (int off=1; off<64; off<<=1){ int u = __shfl_up(inc, off, 64); if (lane>=off) inc += u; }
  if (lane==63) ws[wid] = inc;
  __syncthreads();
  int woff = 0;
  for (int w=0; w<wid; w++) woff += ws[w];
  int base = boff[b] + woff + (inc - tot);
  int pre = 0;
  #pragma unroll
  for (int j=0;j<4;j++){
    int i = i0+j;
    if (i<NN){ rowptr[i] = base + pre; pos[i] = base + pre; }
    pre += d[j];
  }
}

__global__ void k_fill(const int* __restrict__ src, const int* __restrict__ dst,
                       int* __restrict__ pos, int* __restrict__ csr){
  int e = blockIdx.x*256 + threadIdx.x;
  if (e < EE){
    int d = dst[e];
    int p = atomicAdd(&pos[d], 1);
    csr[p] = src[e];
  }
}

// ---------------- weight prep: transpose + fp16 hi/lo split ------------------
// bf16 mode: ph = exact fp16 of the bf16 weight, pl = 0 (single MFMA pass).
// fp32 mode: ph = fp16(w), pl = fp16(w - ph) (two passes).
__global__ void k_prep_w(const int* __restrict__ flags,
    const void* __restrict__ encW, const void* __restrict__ linW1,
    const void* __restrict__ W1, const void* __restrict__ W2,
    unsigned short* __restrict__ ph, unsigned short* __restrict__ pl)
{
  int idx = blockIdx.x*256 + threadIdx.x;   // grid covers 425984
  int fp32 = flags[0];
  const void* src; int off;
  if (idx < 16384){ int n=idx>>7, k=idx&127; src=encW; off=k*128+n; }
  else if (idx < 32768){ int o=idx-16384; int n=o>>7, k=o&127; src=linW1; off=k*128+n; }
  else if (idx < 229376){ int o=idx-32768; int l=o>>15, r=o&32767; int n=r>>7, k=r&127; src=W1; off=l*32768+k*256+n; }
  else { int o=idx-229376; int l=o>>15, r=o&32767; int n=r>>8, k=r&255; src=W2; off=l*32768+k*128+n; }
  float w = fp32 ? ((const float*)src)[off] : bf2f(((const unsigned short*)src)[off]);
  unsigned short h = f2h(w);
  ph[idx] = h;
  pl[idx] = f2h(w - h2f(h));
}

// small params -> fp32, concatenated
#define SM_ENCB 0
#define SM_LNG 128
#define SM_LNB 896
#define SM_TV 1664
#define SM_B1 1670
#define SM_MG 3206
#define SM_MB 4742
#define SM_B2 6278
#define SM_LINB1 7046
#define SM_LINW2 7174
#define SM_LINB2 7430
#define SM_TOT 7432
__global__ void k_prep_small(const int* __restrict__ flags,
    const void* s0, const void* s1, const void* s2, const void* s3,
    const void* s4, const void* s5, const void* s6, const void* s7,
    const void* s8, const void* s9, const void* s10, float* __restrict__ out)
{
  int i = blockIdx.x*256 + threadIdx.x;
  if (i >= SM_TOT) return;
  int fp32 = flags[0];
  const void* src; int off;
  if      (i < SM_LNG)  { src=s0;  off=i; }
  else if (i < SM_LNB)  { src=s1;  off=i-SM_LNG; }
  else if (i < SM_TV)   { src=s2;  off=i-SM_LNB; }
  else if (i < SM_B1)   { src=s3;  off=i-SM_TV; }
  else if (i < SM_MG)   { src=s4;  off=i-SM_B1; }
  else if (i < SM_MB)   { src=s5;  off=i-SM_MG; }
  else if (i < SM_B2)   { src=s6;  off=i-SM_MB; }
  else if (i < SM_LINB1){ src=s7;  off=i-SM_B2; }
  else if (i < SM_LINW2){ src=s8;  off=i-SM_LINB1; }
  else if (i < SM_LINB2){ src=s9;  off=i-SM_LINW2; }
  else                  { src=s10; off=i-SM_LINB2; }
  out[i] = fp32 ? ((const float*)src)[off] : bf2f(((const unsigned short*)src)[off]);
}

// ---------------- generic f16 MFMA GEMM, K=128, tile 64x128 ------------------
// A: aExt=1 -> external float tensor (bf16 or fp32 per flags, cvt to fp16);
//    aExt=0 -> fp16 buffer [M,128].
// EPI: 0 = store fp32, 1 = relu + store fp32.
template<int EPI>
__global__ __launch_bounds__(256, 4) void k_gemm(const void* __restrict__ Ap,
    const unsigned short* __restrict__ WTh, const unsigned short* __restrict__ WTl,
    const float* __restrict__ bias, float* __restrict__ C,
    int M, const int* __restrict__ flags, int aExt)
{
  __shared__ __align__(16) short lA[64*72];
  __shared__ __align__(16) short lW[128*72];

  const int tid = threadIdx.x, lane = tid & 63, wid = tid >> 6;
  const int mi = lane & 15, q = lane >> 4;
  const int rowb = blockIdx.x * 64;
  const int fp32m = flags[0];

  f32x4 acc[4][2];
  #pragma unroll
  for (int a=0;a<4;a++)
    #pragma unroll
    for (int c=0;c<2;c++){ acc[a][c][0]=0.f; acc[a][c][1]=0.f; acc[a][c][2]=0.f; acc[a][c][3]=0.f; }

  const int nW = fp32m ? 2 : 1;
  for (int pass = 0; pass < nW; ++pass){
    const unsigned short* Wp = pass ? WTl : WTh;
    for (int kc = 0; kc < 2; ++kc){
      {
        const int kv = (tid & 7) * 8, r0 = tid >> 3;
        #pragma unroll
        for (int p = 0; p < 2; ++p){
          int row = p*32 + r0, grow = rowb + row;
          uint4 d = make_uint4(0u,0u,0u,0u);
          if (grow < M){
            if (!aExt){
              d = *(const uint4*)((const unsigned short*)Ap + (size_t)grow*128 + kc*64 + kv);
            } else if (!fp32m){
              uint4 u = *(const uint4*)((const unsigned short*)Ap + (size_t)grow*128 + kc*64 + kv);
              const unsigned short* us = (const unsigned short*)&u;
              unsigned short hh[8];
              #pragma unroll
              for (int c=0;c<8;c++) hh[c] = f2h(bf2f(us[c]));
              d.x = hh[0]|((unsigned)hh[1]<<16); d.y = hh[2]|((unsigned)hh[3]<<16);
              d.z = hh[4]|((unsigned)hh[5]<<16); d.w = hh[6]|((unsigned)hh[7]<<16);
            } else {
              const float* fp = (const float*)Ap + (size_t)grow*128 + kc*64 + kv;
              float4 v0 = *(const float4*)fp, v1 = *(const float4*)(fp+4);
              unsigned short hh[8] = {f2h(v0.x),f2h(v0.y),f2h(v0.z),f2h(v0.w),
                                      f2h(v1.x),f2h(v1.y),f2h(v1.z),f2h(v1.w)};
              d.x = hh[0]|((unsigned)hh[1]<<16); d.y = hh[2]|((unsigned)hh[3]<<16);
              d.z = hh[4]|((unsigned)hh[5]<<16); d.w = hh[6]|((unsigned)hh[7]<<16);
            }
          }
          *(uint4*)&lA[row*72 + kv] = d;
        }
        #pragma unroll
        for (int p = 0; p < 4; ++p){
          int n = p*32 + r0;
          *(uint4*)&lW[n*72 + kv] = *(const uint4*)(Wp + (size_t)n*128 + kc*64 + kv);
        }
      }
      __syncthreads();
      #pragma unroll
      for (int ks = 0; ks < 2; ++ks){
        const int koff = ks*32 + q*8;
        f16x8 af[4], bw[2];
        #pragma unroll
        for (int rt=0; rt<4; rt++) af[rt] = *(const f16x8*)&lA[(rt*16+mi)*72 + koff];
        #pragma unroll
        for (int ct=0; ct<2; ct++) bw[ct] = *(const f16x8*)&lW[(wid*32 + ct*16 + mi)*72 + koff];
        #pragma unroll
        for (int rt=0; rt<4; rt++)
          #pragma unroll
          for (int ct=0; ct<2; ct++)
            acc[rt][ct] = __builtin_amdgcn_mfma_f32_16x16x32_f16(af[rt], bw[ct], acc[rt][ct], 0,0,0);
      }
      __syncthreads();
    }
  }
  #pragma unroll
  for (int ct=0; ct<2; ct++){
    const int col = wid*32 + ct*16 + mi;
    const float bf = bias[col];
    #pragma unroll
    for (int rt=0; rt<4; rt++)
      #pragma unroll
      for (int r=0; r<4; r++){
        int row = rowb + rt*16 + q*4 + r;
        if (row < M){
          float v = acc[rt][ct][r] + bf;
          if (EPI == 1) v = fmaxf(v, 0.f);
          C[(size_t)row*128 + col] = v;
        }
      }
  }
}

// ---------------- fused W1 GEMM + LN + relu: z = fp16(relu(LN(A@W1+b1))) -----
// tile 64x256, K=128, BK=64. A fp16 [M,128].
__global__ __launch_bounds__(256, 3) void k_gemm1(const unsigned short* __restrict__ Ap,
    const unsigned short* __restrict__ WTh, const unsigned short* __restrict__ WTl,
    const float* __restrict__ bias, const float* __restrict__ gam, const float* __restrict__ bet,
    unsigned short* __restrict__ z, int M, const int* __restrict__ flags)
{
  __shared__ __align__(16) short lA[64*72];
  __shared__ __align__(16) short lW[256*72];
  __shared__ float2 sred[4][64];

  const int tid = threadIdx.x, lane = tid & 63, wid = tid >> 6;
  const int mi = lane & 15, q = lane >> 4;
  const int rowb = blockIdx.x * 64;

  f32x4 acc[4][4];
  #pragma unroll
  for (int a=0;a<4;a++)
    #pragma unroll
    for (int c=0;c<4;c++){ acc[a][c][0]=0.f; acc[a][c][1]=0.f; acc[a][c][2]=0.f; acc[a][c][3]=0.f; }

  const int nW = flags[0] ? 2 : 1;
  for (int pass = 0; pass < nW; ++pass){
    const unsigned short* Wp = pass ? WTl : WTh;
    for (int kc = 0; kc < 2; ++kc){
      {
        const int kv = (tid & 7) * 8, r0 = tid >> 3;
        #pragma unroll
        for (int p = 0; p < 2; ++p){
          int row = p*32 + r0, grow = rowb + row;
          uint4 d = make_uint4(0u,0u,0u,0u);
          if (grow < M) d = *(const uint4*)(Ap + (size_t)grow*128 + kc*64 + kv);
          *(uint4*)&lA[row*72 + kv] = d;
        }
        #pragma unroll
        for (int p = 0; p < 8; ++p){
          int n = p*32 + r0;
          *(uint4*)&lW[n*72 + kv] = *(const uint4*)(Wp + (size_t)n*128 + kc*64 + kv);
        }
      }
      __syncthreads();
      #pragma unroll
      for (int ks = 0; ks < 2; ++ks){
        const int koff = ks*32 + q*8;
        f16x8 af[4], bw[4];
        #pragma unroll
        for (int rt=0; rt<4; rt++) af[rt] = *(const f16x8*)&lA[(rt*16+mi)*72 + koff];
        #pragma unroll
        for (int ct=0; ct<4; ct++) bw[ct] = *(const f16x8*)&lW[(wid*64 + ct*16 + mi)*72 + koff];
        #pragma unroll
        for (int rt=0; rt<4; rt++)
          #pragma unroll
          for (int ct=0; ct<4; ct++)
            acc[rt][ct] = __builtin_amdgcn_mfma_f32_16x16x32_f16(af[rt], bw[ct], acc[rt][ct], 0,0,0);
      }
      __syncthreads();
    }
  }
  #pragma unroll
  for (int ct=0; ct<4; ct++){
    const float bf = bias[wid*64 + ct*16 + mi];
    #pragma unroll
    for (int rt=0; rt<4; rt++)
      #pragma unroll
      for (int r=0; r<4; r++) acc[rt][ct][r] += bf;
  }
  #pragma unroll
  for (int rt=0; rt<4; rt++)
    #pragma unroll
    for (int r=0; r<4; r++){
      float s = 0.f, s2 = 0.f;
      #pragma unroll
      for (int ct=0; ct<4; ct++){ float v = acc[rt][ct][r]; s += v; s2 += v*v; }
      #pragma unroll
      for (int off=1; off<16; off<<=1){ s += __shfl_xor(s, off, 64); s2 += __shfl_xor(s2, off, 64); }
      if (mi == 0) sred[wid][rt*16 + q*4 + r] = make_float2(s, s2);
    }
  __syncthreads();
  #pragma unroll
  for (int rt=0; rt<4; rt++)
    #pragma unroll
    for (int r=0; r<4; r++){
      int rl = rt*16 + q*4 + r;
      float2 t0 = sred[0][rl], t1 = sred[1][rl], t2 = sred[2][rl], t3 = sred[3][rl];
      float s = t0.x + t1.x + t2.x + t3.x;
      float s2 = t0.y + t1.y + t2.y + t3.y;
      float m = s * (1.f/256.f);
      float var = s2 * (1.f/256.f) - m*m;
      float rs = rsqrtf(var + 1e-5f);
      int row = rowb + rl;
      if (row < M){
        #pragma unroll
        for (int ct=0; ct<4; ct++){
          int col = wid*64 + ct*16 + mi;
          float v = (acc[rt][ct][r] - m) * rs * gam[col] + bet[col];
          z[(size_t)row*256 + col] = f2h(fmaxf(v, 0.f));
        }
      }
    }
}

// ---------------- fused W2 GEMM + residual + next preLN/msg ------------------
// tile 64x128, K=256, BK=64. A = z fp16 [M,256]. h += A@W2 + b2.
// doLN=1: msg = fp16(relu(LN(h))+1e-7); doLN=0: hf = fp16(h).
__global__ __launch_bounds__(256, 4) void k_gemm2(const unsigned short* __restrict__ Ap,
    const unsigned short* __restrict__ WTh, const unsigned short* __restrict__ WTl,
    const float* __restrict__ bias, float* __restrict__ h,
    const float* __restrict__ gam, const float* __restrict__ bet,
    unsigned short* __restrict__ msg, unsigned short* __restrict__ hf,
    int M, const int* __restrict__ flags, int doLN)
{
  __shared__ __align__(16) short lA[64*72];
  __shared__ __align__(16) short lW[128*72];
  __shared__ float2 sred[4][64];

  const int tid = threadIdx.x, lane = tid & 63, wid = tid >> 6;
  const int mi = lane & 15, q = lane >> 4;
  const int rowb = blockIdx.x * 64;

  f32x4 acc[4][2];
  #pragma unroll
  for (int a=0;a<4;a++)
    #pragma unroll
    for (int c=0;c<2;c++){ acc[a][c][0]=0.f; acc[a][c][1]=0.f; acc[a][c][2]=0.f; acc[a][c][3]=0.f; }

  const int nW = flags[0] ? 2 : 1;
  for (int pass = 0; pass < nW; ++pass){
    const unsigned short* Wp = pass ? WTl : WTh;
    for (int kc = 0; kc < 4; ++kc){
      {
        const int kv = (tid & 7) * 8, r0 = tid >> 3;
        #pragma unroll
        for (int p = 0; p < 2; ++p){
          int row = p*32 + r0, grow = rowb + row;
          uint4 d = make_uint4(0u,0u,0u,0u);
          if (grow < M) d = *(const uint4*)(Ap + (size_t)grow*256 + kc*64 + kv);
          *(uint4*)&lA[row*72 + kv] = d;
        }
        #pragma unroll
        for (int p = 0; p < 4; ++p){
          int n = p*32 + r0;
          *(uint4*)&lW[n*72 + kv] = *(const uint4*)(Wp + (size_t)n*256 + kc*64 + kv);
        }
      }
      __syncthreads();
      #pragma unroll
      for (int ks = 0; ks < 2; ++ks){
        const int koff = ks*32 + q*8;
        f16x8 af[4], bw[2];
        #pragma unroll
        for (int rt=0; rt<4; rt++) af[rt] = *(const f16x8*)&lA[(rt*16+mi)*72 + koff];
        #pragma unroll
        for (int ct=0; ct<2; ct++) bw[ct] = *(const f16x8*)&lW[(wid*32 + ct*16 + mi)*72 + koff];
        #pragma unroll
        for (int rt=0; rt<4; rt++)
          #pragma unroll
          for (int ct=0; ct<2; ct++)
            acc[rt][ct] = __builtin_amdgcn_mfma_f32_16x16x32_f16(af[rt], bw[ct], acc[rt][ct], 0,0,0);
      }
      __syncthreads();
    }
  }
  // residual add + write h; keep hnew in acc
  #pragma unroll
  for (int ct=0; ct<2; ct++){
    const int col = wid*32 + ct*16 + mi;
    const float bf = bias[col];
    #pragma unroll
    for (int rt=0; rt<4; rt++)
      #pragma unroll
      for (int r=0; r<4; r++){
        int row = rowb + rt*16 + q*4 + r;
        if (row < M){
          float hv = acc[rt][ct][r] + bf + h[(size_t)row*128 + col];
          h[(size_t)row*128 + col] = hv;
          acc[rt][ct][r] = hv;
        }
      }
  }
  if (!doLN){
    #pragma unroll
    for (int ct=0; ct<2; ct++){
      const int col = wid*32 + ct*16 + mi;
      #pragma unroll
      for (int rt=0; rt<4; rt++)
        #pragma unroll
        for (int r=0; r<4; r++){
          int row = rowb + rt*16 + q*4 + r;
          if (row < M) hf[(size_t)row*128 + col] = f2h(acc[rt][ct][r]);
        }
    }
    return;
  }
  #pragma unroll
  for (int rt=0; rt<4; rt++)
    #pragma unroll
    for (int r=0; r<4; r++){
      float s = 0.f, s2 = 0.f;
      #pragma unroll
      for (int ct=0; ct<2; ct++){ float v = acc[rt][ct][r]; s += v; s2 += v*v; }
      #pragma unroll
      for (int off=1; off<16; off<<=1){ s += __shfl_xor(s, off, 64); s2 += __shfl_xor(s2, off, 64); }
      if (mi == 0) sred[wid][rt*16 + q*4 + r] = make_float2(s, s2);
    }
  __syncthreads();
  #pragma unroll
  for (int rt=0; rt<4; rt++)
    #pragma unroll
    for (int r=0; r<4; r++){
      int rl = rt*16 + q*4 + r;
      float2 t0 = sred[0][rl], t1 = sred[1][rl], t2 = sred[2][rl], t3 = sred[3][rl];
      float s = t0.x + t1.x + t2.x + t3.x;
      float s2 = t0.y + t1.y + t2.y + t3.y;
      float m = s * (1.f/128.f);
      float var = s2 * (1.f/128.f) - m*m;
      float rs = rsqrtf(var + 1e-5f);
      int row = rowb + rl;
      if (row < M){
        #pragma unroll
        for (int ct=0; ct<2; ct++){
          int col = wid*32 + ct*16 + mi;
          float g = fmaxf((acc[rt][ct][r] - m) * rs * gam[col] + bet[col], 0.f);
          msg[(size_t)row*128 + col] = f2h(g + 1e-7f);
        }
      }
    }
}

// ---------------- layer-0 pre-LN: msg = fp16(relu(LN(h)) + 1e-7) -------------
__global__ __launch_bounds__(256,4) void k_preln0(const float* __restrict__ h,
    const float* __restrict__ gam, const float* __restrict__ bet,
    unsigned short* __restrict__ msg)
{
  int wid = threadIdx.x >> 6, lane = threadIdx.x & 63;
  int row = blockIdx.x*4 + wid;
  float2 v = ((const float2*)(h + (size_t)row*DD))[lane];
  float mean = wave_sum(v.x+v.y) * (1.f/128.f);
  float d0 = v.x-mean, d1 = v.y-mean;
  float var = wave_sum(d0*d0 + d1*d1) * (1.f/128.f);
  float rs = rsqrtf(var + 1e-5f);
  float o0 = fmaxf(d0*rs*gam[2*lane]   + bet[2*lane],   0.f);
  float o1 = fmaxf(d1*rs*gam[2*lane+1] + bet[2*lane+1], 0.f);
  unsigned u = (unsigned)f2h(o0 + 1e-7f) | ((unsigned)f2h(o1 + 1e-7f) << 16);
  ((unsigned*)(msg + (size_t)row*DD))[lane] = u;
}

// ---------------- softmax aggregation: 4 edges/iter, fp16 out ----------------
__global__ __launch_bounds__(256,4) void k_agg(
    const unsigned short* __restrict__ msg,
    const int* __restrict__ rowptr, const int* __restrict__ csr,
    const float* __restrict__ tp, unsigned short* __restrict__ obf)
{
  int wid = threadIdx.x>>6, lane = threadIdx.x&63;
  int node = blockIdx.x*4 + wid;
  float t = tp[0];
  int st = rowptr[node], en = rowptr[node+1];
  int quad = lane >> 4, fi = lane & 15;
  float l[8], ac[8];
  #pragma unroll
  for (int f=0; f<8; f++){ l[f]=0.f; ac[f]=0.f; }
  for (int base = st; base < en; base += 64){
    int cnt = min(64, en - base);
    int sv = (lane < cnt) ? csr[base + lane] : 0;
    for (int j = 0; j < cnt; j += 4){
      int idx = j + quad;
      int s = __shfl(sv, idx, 64);
      bool val = idx < cnt;
      uint4 u = *(const uint4*)(msg + (size_t)s*DD + fi*8);
      float m[8];
      m[0]=h2f((unsigned short)(u.x&0xffffu)); m[1]=h2f((unsigned short)(u.x>>16));
      m[2]=h2f((unsigned short)(u.y&0xffffu)); m[3]=h2f((unsigned short)(u.y>>16));
      m[4]=h2f((unsigned short)(u.z&0xffffu)); m[5]=h2f((unsigned short)(u.z>>16));
      m[6]=h2f((unsigned short)(u.w&0xffffu)); m[7]=h2f((unsigned short)(u.w>>16));
      #pragma unroll
      for (int f=0; f<8; f++){
        float e = __expf(fminf(m[f]*t, 80.f));
        e = val ? e : 0.f;
        l[f] += e; ac[f] += m[f]*e;
      }
    }
  }
  #pragma unroll
  for (int off=16; off<=32; off<<=1)
    #pragma unroll
    for (int f=0; f<8; f++){ l[f] += __shfl_xor(l[f], off, 64); ac[f] += __shfl_xor(ac[f], off, 64); }
  if (quad == 0){
    uint4 u = *(const uint4*)(msg + (size_t)node*DD + fi*8);
    float m[8];
    m[0]=h2f((unsigned short)(u.x&0xffffu)); m[1]=h2f((unsigned short)(u.x>>16));
    m[2]=h2f((unsigned short)(u.y&0xffffu)); m[3]=h2f((unsigned short)(u.y>>16));
    m[4]=h2f((unsigned short)(u.z&0xffffu)); m[5]=h2f((unsigned short)(u.z>>16));
    m[6]=h2f((unsigned short)(u.w&0xffffu)); m[7]=h2f((unsigned short)(u.w>>16));
    bool has = en > st;
    unsigned short o[8];
    #pragma unroll
    for (int f=0; f<8; f++){
      float a = has ? (ac[f] / (l[f] + 1e-16f)) : 0.f;
      o[f] = f2h((m[f] - 1e-7f) + a);
    }
    uint4 w;
    w.x = o[0]|((unsigned)o[1]<<16); w.y = o[2]|((unsigned)o[3]<<16);
    w.z = o[4]|((unsigned)o[5]<<16); w.w = o[6]|((unsigned)o[7]<<16);
    *(uint4*)(obf + (size_t)node*DD + fi*8) = w;
  }
}

// ---------------- head ----------------
__global__ __launch_bounds__(256,4) void k_head2(const float* __restrict__ u,
    const float* __restrict__ w, const float* __restrict__ b,
    void* __restrict__ out, const int* __restrict__ flags)
{
  int wid = threadIdx.x>>6, lane = threadIdx.x&63;
  int row = blockIdx.x*4 + wid;
  const float* ur = u + (size_t)row*DD;
  float u0 = ur[lane], u1 = ur[lane+64];
  float s0 = u0*w[lane*2+0] + u1*w[(lane+64)*2+0];
  float s1 = u0*w[lane*2+1] + u1*w[(lane+64)*2+1];
  s0 = wave_sum(s0); s1 = wave_sum(s1);
  if (lane == 0){
    float o0 = s0 + b[0], o1 = s1 + b[1];
    if (flags[0]){
      ((float*)out)[row*2+0] = o0;
      ((float*)out)[row*2+1] = o1;
    } else {
      ((unsigned short*)out)[row*2+0] = f2bf(o0);
      ((unsigned short*)out)[row*2+1] = f2bf(o1);
    }
  }
}

extern "C" void kernel_launch(void* const* d_in, const int* in_sizes, int n_in,
                              void* d_out, int out_size, void* d_ws, size_t ws_size,
                              hipStream_t stream)
{
  (void)in_sizes; (void)n_in; (void)out_size; (void)ws_size;
  char* ws = (char*)d_ws;
  size_t off = 0;
  auto alloc = [&](size_t bytes) -> char* {
    char* p = ws + off;
    off = (off + bytes + 255) & ~(size_t)255;
    return p;
  };
  int* flags  = (int*)alloc(256);
  float* sm   = (float*)alloc(SM_TOT*4);
  unsigned short* planeH = (unsigned short*)alloc(425984*2);
  unsigned short* planeL = (unsigned short*)alloc(425984*2);
  int* src32  = (int*)alloc((size_t)EE*4);
  int* dst32  = (int*)alloc((size_t)EE*4);
  int* deg    = (int*)alloc((size_t)NN*4);
  int* pos    = (int*)alloc((size_t)NN*4);
  int* rowptr = (int*)alloc((size_t)(NN+1)*4);
  int* csr    = (int*)alloc((size_t)EE*4);
  int* bsum   = (int*)alloc(64*4);
  int* boff   = (int*)alloc(64*4);
  float* h    = (float*)alloc((size_t)NN*128*4);
  unsigned short* z    = (unsigned short*)alloc((size_t)NN*256*2);
  unsigned short* msgb = (unsigned short*)alloc((size_t)NN*128*2);
  unsigned short* obf  = (unsigned short*)alloc((size_t)NN*128*2);
  unsigned short* hf   = (unsigned short*)alloc((size_t)NN*128*2);
  float* ob   = (float*)alloc((size_t)NN*128*4);

  k_detect<<<1,256,0,stream>>>((const unsigned short*)d_in[0], (const unsigned int*)d_in[1], flags);
  k_cvt_edges<<<(EE+255)/256,256,0,stream>>>(d_in[1], flags, src32, dst32);
  hipMemsetAsync(deg, 0, (size_t)NN*4, stream);
  k_hist<<<(EE+255)/256,256,0,stream>>>(dst32, deg);
  k_blocksum<<<NB,256,0,stream>>>(deg, bsum);
  k_scanb<<<1,64,0,stream>>>(bsum, boff, rowptr);
  k_scanscatter<<<NB,256,0,stream>>>(deg, boff, rowptr, pos);
  k_fill<<<(EE+255)/256,256,0,stream>>>(src32, dst32, pos, csr);
  k_prep_w<<<1664,256,0,stream>>>(flags, d_in[2], d_in[13], d_in[7], d_in[11], planeH, planeL);
  k_prep_small<<<30,256,0,stream>>>(flags, d_in[3], d_in[4], d_in[5], d_in[6], d_in[8],
                                    d_in[9], d_in[10], d_in[12], d_in[14], d_in[15], d_in[16], sm);

  const int GB = (NN + 63)/64;  // 782
  // encoder: h = x @ enc_W + enc_b
  k_gemm<0><<<GB,256,0,stream>>>((const void*)d_in[0], planeH + 0, planeL + 0,
                                 sm + SM_ENCB, h, NN, flags, 1);
  k_preln0<<<NN/4,256,0,stream>>>(h, sm + SM_LNG, sm + SM_LNB, msgb);
  for (int i = 0; i < LL; ++i){
    k_agg<<<NN/4,256,0,stream>>>(msgb, rowptr, csr, sm + SM_TV + i, obf);
    k_gemm1<<<GB,256,0,stream>>>(obf, planeH + 32768 + i*32768, planeL + 32768 + i*32768,
                                 sm + SM_B1 + i*256, sm + SM_MG + i*256, sm + SM_MB + i*256,
                                 z, NN, flags);
    int nl = (i+1 < LL) ? (i+1) : 0;
    k_gemm2<<<GB,256,0,stream>>>(z, planeH + 229376 + i*32768, planeL + 229376 + i*32768,
                                 sm + SM_B2 + i*128, h,
                                 sm + SM_LNG + nl*128, sm + SM_LNB + nl*128,
                                 msgb, hf, NN, flags, (i+1 < LL) ? 1 : 0);
  }
  // head: ob = relu(hf @ lin_W1 + lin_b1)
  k_gemm<1><<<GB,256,0,stream>>>((const void*)hf, planeH + 16384, planeL + 16384,
                                 sm + SM_LINB1, ob, NN, flags, 0);
  k_head2<<<NN/4,256,0,stream>>>(ob, sm + SM_LINW2, sm + SM_LINB2, d_out, flags);
}